// Round 3
// baseline (281.278 us; speedup 1.0000x reference)
//
#include <hip/hip_runtime.h>
#include <stdint.h>

typedef __attribute__((ext_vector_type(8))) short short8;
typedef __attribute__((ext_vector_type(4))) float f32x4;
typedef __attribute__((ext_vector_type(2))) unsigned int u32x2;

// fp32 -> bf16 round-to-nearest-even, returned in low 16 bits
static __device__ __forceinline__ uint32_t f2bf1(float f) {
    union { float f; uint32_t u; } v; v.f = f;
    return (v.u + 0x7FFFu + ((v.u >> 16) & 1u)) >> 16;
}

// XOR-swizzle on 16B granules within an 8KB buffer: inject row bits into bank bits.
// Bijective involution (bits 4-6 of granule index XORed into bits 0-2).
static __device__ __forceinline__ int swz(int byteoff) {
    int g = byteoff >> 4;
    g ^= (g >> 4) & 7;
    return (g << 4) | (byteoff & 15);
}

__global__ __launch_bounds__(256, 4) void bl_kernel(
    const float* __restrict__ x, const float* __restrict__ w1,
    const float* __restrict__ w2, float* __restrict__ out, int ntok)
{
    __shared__ __align__(16) uint8_t xlds[8192];   // X tile, [32][128] bf16, swizzled
    __shared__ __align__(16) uint8_t a2lds[8192];  // permuted intermediate, same layout

    const int tid  = threadIdx.x;
    const int wid  = tid >> 6;    // wave 0..3 -> owns output cols [wid*32, wid*32+32)
    const int lane = tid & 63;
    const int lrow = lane & 15;   // MFMA fragment row/col index
    const int lgrp = lane >> 4;   // MFMA k-octet group

    // ---- Load W1/W2 B-fragments into registers (held for whole kernel) ----
    // B-frag for 16x16x32: n = lane&15, k = 8*(lane>>4)+i ; frag (nt, ks) covers
    // cols [ (wid*2+nt)*16 , +16 ), k rows [ks*32, ks*32+32)
    short8 wf0[2][4], wf1[2][4];
#pragma unroll
    for (int nt = 0; nt < 2; ++nt) {
        const int col = (wid * 2 + nt) * 16 + lrow;
#pragma unroll
        for (int ks = 0; ks < 4; ++ks) {
            short8 f0, f1;
#pragma unroll
            for (int i = 0; i < 8; ++i) {
                const int rowk = ks * 32 + lgrp * 8 + i;
                f0[i] = (short)f2bf1(w1[rowk * 128 + col]);
                f1[i] = (short)f2bf1(w2[rowk * 128 + col]);
            }
            wf0[nt][ks] = f0;
            wf1[nt][ks] = f1;
        }
    }

    const int stride = gridDim.x;
    f32x4 xr[4];
    const int t0 = blockIdx.x;
    if (t0 < ntok) {
        const f32x4* p = (const f32x4*)(x + (size_t)t0 * 4096);
#pragma unroll
        for (int k = 0; k < 4; ++k) xr[k] = __builtin_nontemporal_load(p + tid + 256 * k);
    }

    for (int t = t0; t < ntok; t += stride) {
        // ---- stage current token to LDS (bf16), prefetch next token ----
        u32x2 pk[4];
#pragma unroll
        for (int k = 0; k < 4; ++k) {
            pk[k][0] = f2bf1(xr[k][0]) | (f2bf1(xr[k][1]) << 16);
            pk[k][1] = f2bf1(xr[k][2]) | (f2bf1(xr[k][3]) << 16);
        }
        const int tn = t + stride;
        if (tn < ntok) {
            const f32x4* p = (const f32x4*)(x + (size_t)tn * 4096);
#pragma unroll
            for (int k = 0; k < 4; ++k) xr[k] = __builtin_nontemporal_load(p + tid + 256 * k);
        }
        // thread holds floats at flat idx 4*tid + 1024*k -> bf16 bytes at 8*tid + 2048*k
#pragma unroll
        for (int k = 0; k < 4; ++k) {
            *(u32x2*)(xlds + swz(8 * tid + 2048 * k)) = pk[k];
        }
        __syncthreads();  // B0: xlds ready; prev iter's a2lds reads done

        // ---- step 1: C1 = X * W1 (this wave: cols [wid*32, +32)) ----
        f32x4 acc[2][2];
#pragma unroll
        for (int mt = 0; mt < 2; ++mt)
#pragma unroll
            for (int nt = 0; nt < 2; ++nt)
                acc[mt][nt] = (f32x4){0.f, 0.f, 0.f, 0.f};
#pragma unroll
        for (int ks = 0; ks < 4; ++ks) {
            short8 af0 = *(const short8*)(xlds +
                swz(((0 * 16 + lrow) * 128 + ks * 32 + lgrp * 8) * 2));
            short8 af1 = *(const short8*)(xlds +
                swz(((1 * 16 + lrow) * 128 + ks * 32 + lgrp * 8) * 2));
#pragma unroll
            for (int nt = 0; nt < 2; ++nt) {
                acc[0][nt] = __builtin_amdgcn_mfma_f32_16x16x32_bf16(
                    af0, wf0[nt][ks], acc[0][nt], 0, 0, 0);
                acc[1][nt] = __builtin_amdgcn_mfma_f32_16x16x32_bf16(
                    af1, wf0[nt][ks], acc[1][nt], 0, 0, 0);
            }
        }

        // ---- permutation scatter: C1[r][n] -> flat[n*32 + r] (bf16 into a2lds) ----
        // lane's 4 regs are consecutive r at fixed n -> one ds_write_b64
#pragma unroll
        for (int mt = 0; mt < 2; ++mt)
#pragma unroll
            for (int nt = 0; nt < 2; ++nt) {
                const int n  = (wid * 2 + nt) * 16 + lrow;
                const int r0 = mt * 16 + lgrp * 4;
                u32x2 v;
                v[0] = f2bf1(acc[mt][nt][0]) | (f2bf1(acc[mt][nt][1]) << 16);
                v[1] = f2bf1(acc[mt][nt][2]) | (f2bf1(acc[mt][nt][3]) << 16);
                *(u32x2*)(a2lds + swz((n * 32 + r0) * 2)) = v;
            }
        __syncthreads();  // B1: a2lds ready; xlds reads done

        // ---- step 2: C2 = A2 * W2 ----
        f32x4 acc2[2][2];
#pragma unroll
        for (int mt = 0; mt < 2; ++mt)
#pragma unroll
            for (int nt = 0; nt < 2; ++nt)
                acc2[mt][nt] = (f32x4){0.f, 0.f, 0.f, 0.f};
#pragma unroll
        for (int ks = 0; ks < 4; ++ks) {
            short8 af0 = *(const short8*)(a2lds +
                swz(((0 * 16 + lrow) * 128 + ks * 32 + lgrp * 8) * 2));
            short8 af1 = *(const short8*)(a2lds +
                swz(((1 * 16 + lrow) * 128 + ks * 32 + lgrp * 8) * 2));
#pragma unroll
            for (int nt = 0; nt < 2; ++nt) {
                acc2[0][nt] = __builtin_amdgcn_mfma_f32_16x16x32_bf16(
                    af0, wf1[nt][ks], acc2[0][nt], 0, 0, 0);
                acc2[1][nt] = __builtin_amdgcn_mfma_f32_16x16x32_bf16(
                    af1, wf1[nt][ks], acc2[1][nt], 0, 0, 0);
            }
        }

        // ---- final permuted store: out[t*4096 + n*32 + r] = C2[r][n] (fp32) ----
        float* op = out + (size_t)t * 4096;
#pragma unroll
        for (int mt = 0; mt < 2; ++mt)
#pragma unroll
            for (int nt = 0; nt < 2; ++nt) {
                const int n  = (wid * 2 + nt) * 16 + lrow;
                const int r0 = mt * 16 + lgrp * 4;
                f32x4 o = (f32x4){acc2[mt][nt][0], acc2[mt][nt][1],
                                  acc2[mt][nt][2], acc2[mt][nt][3]};
                __builtin_nontemporal_store(o, (f32x4*)(op + n * 32 + r0));
            }
        // no barrier needed here: next iter's B0 orders a2lds reads vs writes,
        // and B1 already ordered xlds reads vs next iter's xlds writes.
    }
}

extern "C" void kernel_launch(void* const* d_in, const int* in_sizes, int n_in,
                              void* d_out, int out_size, void* d_ws, size_t ws_size,
                              hipStream_t stream) {
    const float* x  = (const float*)d_in[0];
    const float* w1 = (const float*)d_in[1];
    const float* w2 = (const float*)d_in[2];
    float* out = (float*)d_out;
    const int ntok = in_sizes[0] / 4096;  // 32768 for the bench shape
    const int nwg = 1024;                 // 4 blocks/CU x 256 CUs, exactly resident
    hipLaunchKernelGGL(bl_kernel, dim3(nwg), dim3(256), 0, stream,
                       x, w1, w2, out, ntok);
}

// Round 4
// 207.958 us; speedup vs baseline: 1.3526x; 1.3526x over previous
//
#include <hip/hip_runtime.h>
#include <stdint.h>

typedef __attribute__((ext_vector_type(8))) short short8;
typedef __attribute__((ext_vector_type(4))) float f32x4;
typedef __attribute__((ext_vector_type(2))) unsigned int u32x2;

// fp32 -> bf16 round-to-nearest-even, returned in low 16 bits
static __device__ __forceinline__ uint32_t f2bf1(float f) {
    union { float f; uint32_t u; } v; v.f = f;
    return (v.u + 0x7FFFu + ((v.u >> 16) & 1u)) >> 16;
}

// XOR-swizzle on 16B granules within an 8KB buffer: inject row bits into bank bits.
// Bijective involution (bits 4-6 of granule index XORed into bits 0-2).
static __device__ __forceinline__ int swz(int byteoff) {
    int g = byteoff >> 4;
    g ^= (g >> 4) & 7;
    return (g << 4) | (byteoff & 15);
}

__global__ __launch_bounds__(256, 3) void bl_kernel(
    const float* __restrict__ x, const float* __restrict__ w1,
    const float* __restrict__ w2, float* __restrict__ out, int ntok)
{
    __shared__ __align__(16) uint8_t xlds[8192];   // X tile, [32][128] bf16, swizzled
    __shared__ __align__(16) uint8_t a2lds[8192];  // permuted intermediate, same layout

    const int tid  = threadIdx.x;
    const int wid  = tid >> 6;    // wave 0..3 -> owns output cols [wid*32, wid*32+32)
    const int lane = tid & 63;
    const int lrow = lane & 15;   // MFMA fragment row/col index
    const int lgrp = lane >> 4;   // MFMA k-octet group

    // ---- Load W1/W2 B-fragments into registers (held for whole kernel) ----
    // B-frag for 16x16x32: n = lane&15, k = 8*(lane>>4)+i ; frag (nt, ks) covers
    // cols [ (wid*2+nt)*16 , +16 ), k rows [ks*32, ks*32+32)
    short8 wf0[2][4], wf1[2][4];
#pragma unroll
    for (int nt = 0; nt < 2; ++nt) {
        const int col = (wid * 2 + nt) * 16 + lrow;
#pragma unroll
        for (int ks = 0; ks < 4; ++ks) {
            short8 f0, f1;
#pragma unroll
            for (int i = 0; i < 8; ++i) {
                const int rowk = ks * 32 + lgrp * 8 + i;
                f0[i] = (short)f2bf1(w1[rowk * 128 + col]);
                f1[i] = (short)f2bf1(w2[rowk * 128 + col]);
            }
            wf0[nt][ks] = f0;
            wf1[nt][ks] = f1;
        }
    }

    const int stride = gridDim.x;
    f32x4 xr[4];
    const int t0 = blockIdx.x;
    if (t0 < ntok) {
        const f32x4* p = (const f32x4*)(x + (size_t)t0 * 4096);
#pragma unroll
        for (int k = 0; k < 4; ++k) xr[k] = p[tid + 256 * k];
    }

    for (int t = t0; t < ntok; t += stride) {
        // ---- stage current token to LDS (bf16), prefetch next token ----
        u32x2 pk[4];
#pragma unroll
        for (int k = 0; k < 4; ++k) {
            pk[k][0] = f2bf1(xr[k][0]) | (f2bf1(xr[k][1]) << 16);
            pk[k][1] = f2bf1(xr[k][2]) | (f2bf1(xr[k][3]) << 16);
        }
        const int tn = t + stride;
        if (tn < ntok) {
            const f32x4* p = (const f32x4*)(x + (size_t)tn * 4096);
#pragma unroll
            for (int k = 0; k < 4; ++k) xr[k] = p[tid + 256 * k];
        }
        // thread holds floats at flat idx 4*tid + 1024*k -> bf16 bytes at 8*tid + 2048*k
#pragma unroll
        for (int k = 0; k < 4; ++k) {
            *(u32x2*)(xlds + swz(8 * tid + 2048 * k)) = pk[k];
        }
        __syncthreads();  // B0: xlds ready; prev iter's a2lds reads done

        // ---- step 1: C1 = X * W1 (this wave: cols [wid*32, +32)) ----
        f32x4 acc[2][2];
#pragma unroll
        for (int mt = 0; mt < 2; ++mt)
#pragma unroll
            for (int nt = 0; nt < 2; ++nt)
                acc[mt][nt] = (f32x4){0.f, 0.f, 0.f, 0.f};
#pragma unroll
        for (int ks = 0; ks < 4; ++ks) {
            short8 af0 = *(const short8*)(xlds +
                swz(((0 * 16 + lrow) * 128 + ks * 32 + lgrp * 8) * 2));
            short8 af1 = *(const short8*)(xlds +
                swz(((1 * 16 + lrow) * 128 + ks * 32 + lgrp * 8) * 2));
#pragma unroll
            for (int nt = 0; nt < 2; ++nt) {
                acc[0][nt] = __builtin_amdgcn_mfma_f32_16x16x32_bf16(
                    af0, wf0[nt][ks], acc[0][nt], 0, 0, 0);
                acc[1][nt] = __builtin_amdgcn_mfma_f32_16x16x32_bf16(
                    af1, wf0[nt][ks], acc[1][nt], 0, 0, 0);
            }
        }

        // ---- permutation scatter: C1[r][n] -> flat[n*32 + r] (bf16 into a2lds) ----
        // lane's 4 regs are consecutive r at fixed n -> one ds_write_b64
#pragma unroll
        for (int mt = 0; mt < 2; ++mt)
#pragma unroll
            for (int nt = 0; nt < 2; ++nt) {
                const int n  = (wid * 2 + nt) * 16 + lrow;
                const int r0 = mt * 16 + lgrp * 4;
                u32x2 v;
                v[0] = f2bf1(acc[mt][nt][0]) | (f2bf1(acc[mt][nt][1]) << 16);
                v[1] = f2bf1(acc[mt][nt][2]) | (f2bf1(acc[mt][nt][3]) << 16);
                *(u32x2*)(a2lds + swz((n * 32 + r0) * 2)) = v;
            }
        __syncthreads();  // B1: a2lds ready; xlds reads done

        // ---- step 2: C2 = A2 * W2 ----
        f32x4 acc2[2][2];
#pragma unroll
        for (int mt = 0; mt < 2; ++mt)
#pragma unroll
            for (int nt = 0; nt < 2; ++nt)
                acc2[mt][nt] = (f32x4){0.f, 0.f, 0.f, 0.f};
#pragma unroll
        for (int ks = 0; ks < 4; ++ks) {
            short8 af0 = *(const short8*)(a2lds +
                swz(((0 * 16 + lrow) * 128 + ks * 32 + lgrp * 8) * 2));
            short8 af1 = *(const short8*)(a2lds +
                swz(((1 * 16 + lrow) * 128 + ks * 32 + lgrp * 8) * 2));
#pragma unroll
            for (int nt = 0; nt < 2; ++nt) {
                acc2[0][nt] = __builtin_amdgcn_mfma_f32_16x16x32_bf16(
                    af0, wf1[nt][ks], acc2[0][nt], 0, 0, 0);
                acc2[1][nt] = __builtin_amdgcn_mfma_f32_16x16x32_bf16(
                    af1, wf1[nt][ks], acc2[1][nt], 0, 0, 0);
            }
        }

        // ---- final permuted store: out[t*4096 + n*32 + r] = C2[r][n] (fp32) ----
        float* op = out + (size_t)t * 4096;
#pragma unroll
        for (int mt = 0; mt < 2; ++mt)
#pragma unroll
            for (int nt = 0; nt < 2; ++nt) {
                const int n  = (wid * 2 + nt) * 16 + lrow;
                const int r0 = mt * 16 + lgrp * 4;
                f32x4 o = (f32x4){acc2[mt][nt][0], acc2[mt][nt][1],
                                  acc2[mt][nt][2], acc2[mt][nt][3]};
                *(f32x4*)(op + n * 32 + r0) = o;
            }
        // no barrier needed here: next iter's B0 orders a2lds reads vs writes,
        // and B1 already ordered xlds reads vs next iter's xlds writes.
    }
}

extern "C" void kernel_launch(void* const* d_in, const int* in_sizes, int n_in,
                              void* d_out, int out_size, void* d_ws, size_t ws_size,
                              hipStream_t stream) {
    const float* x  = (const float*)d_in[0];
    const float* w1 = (const float*)d_in[1];
    const float* w2 = (const float*)d_in[2];
    float* out = (float*)d_out;
    const int ntok = in_sizes[0] / 4096;  // 32768 for the bench shape
    const int nwg = 2048;
    hipLaunchKernelGGL(bl_kernel, dim3(nwg), dim3(256), 0, stream,
                       x, w1, w2, out, ntok);
}

// Round 5
// 207.284 us; speedup vs baseline: 1.3570x; 1.0033x over previous
//
#include <hip/hip_runtime.h>
#include <stdint.h>

typedef __attribute__((ext_vector_type(8))) short short8;
typedef __attribute__((ext_vector_type(4))) float f32x4;
typedef __attribute__((ext_vector_type(2))) unsigned int u32x2;

// fp32 -> bf16 round-to-nearest-even, returned in low 16 bits
static __device__ __forceinline__ uint32_t f2bf1(float f) {
    union { float f; uint32_t u; } v; v.f = f;
    return (v.u + 0x7FFFu + ((v.u >> 16) & 1u)) >> 16;
}

// XOR-swizzle on 16B granules: inject row bits into bank bits.
// Bijective involution (bits 4-6 of granule index XORed into bits 0-2).
static __device__ __forceinline__ int swz(int byteoff) {
    int g = byteoff >> 4;
    g ^= (g >> 4) & 7;
    return (g << 4) | (byteoff & 15);
}

__global__ __launch_bounds__(256, 3) void bl_kernel(
    const float* __restrict__ x, const float* __restrict__ w1,
    const float* __restrict__ w2, float* __restrict__ out, int ntok)
{
    __shared__ __align__(16) uint8_t xlds[8192];    // X tile, [32][128] bf16, swizzled
    __shared__ __align__(16) uint8_t a2lds[8192];   // permuted intermediate, same layout
    __shared__ __align__(16) uint8_t obuf[16384];   // per-wave 4KB output re-layout

    const int tid  = threadIdx.x;
    const int wid  = tid >> 6;    // wave 0..3 -> owns output cols [wid*32, wid*32+32)
    const int lane = tid & 63;
    const int lrow = lane & 15;   // MFMA fragment row/col index
    const int lgrp = lane >> 4;   // MFMA k-octet group

    // ---- Load W1/W2 B-fragments into registers (held for whole kernel) ----
    // B-frag for 16x16x32: n = lane&15, k = 8*(lane>>4)+i ; frag (nt, ks) covers
    // cols [ (wid*2+nt)*16 , +16 ), k rows [ks*32, ks*32+32)
    short8 wf0[2][4], wf1[2][4];
#pragma unroll
    for (int nt = 0; nt < 2; ++nt) {
        const int col = (wid * 2 + nt) * 16 + lrow;
#pragma unroll
        for (int ks = 0; ks < 4; ++ks) {
            short8 f0, f1;
#pragma unroll
            for (int i = 0; i < 8; ++i) {
                const int rowk = ks * 32 + lgrp * 8 + i;
                f0[i] = (short)f2bf1(w1[rowk * 128 + col]);
                f1[i] = (short)f2bf1(w2[rowk * 128 + col]);
            }
            wf0[nt][ks] = f0;
            wf1[nt][ks] = f1;
        }
    }

    const int stride = gridDim.x;
    f32x4 xr[4];
    const int t0 = blockIdx.x;
    if (t0 < ntok) {
        const f32x4* p = (const f32x4*)(x + (size_t)t0 * 4096);
#pragma unroll
        for (int k = 0; k < 4; ++k) xr[k] = p[tid + 256 * k];
    }

    for (int t = t0; t < ntok; t += stride) {
        // ---- stage current token to LDS (bf16), prefetch next token ----
        u32x2 pk[4];
#pragma unroll
        for (int k = 0; k < 4; ++k) {
            pk[k][0] = f2bf1(xr[k][0]) | (f2bf1(xr[k][1]) << 16);
            pk[k][1] = f2bf1(xr[k][2]) | (f2bf1(xr[k][3]) << 16);
        }
        const int tn = t + stride;
        if (tn < ntok) {
            const f32x4* p = (const f32x4*)(x + (size_t)tn * 4096);
#pragma unroll
            for (int k = 0; k < 4; ++k) xr[k] = p[tid + 256 * k];
        }
        // thread holds floats at flat idx 4*tid + 1024*k -> bf16 bytes at 8*tid + 2048*k
#pragma unroll
        for (int k = 0; k < 4; ++k) {
            *(u32x2*)(xlds + swz(8 * tid + 2048 * k)) = pk[k];
        }
        __syncthreads();  // B0: xlds ready; prev iter's a2lds reads done

        // ---- step 1: C1 = X * W1 (this wave: cols [wid*32, +32)) ----
        f32x4 acc[2][2];
#pragma unroll
        for (int mt = 0; mt < 2; ++mt)
#pragma unroll
            for (int nt = 0; nt < 2; ++nt)
                acc[mt][nt] = (f32x4){0.f, 0.f, 0.f, 0.f};
#pragma unroll
        for (int ks = 0; ks < 4; ++ks) {
            short8 af0 = *(const short8*)(xlds +
                swz(((0 * 16 + lrow) * 128 + ks * 32 + lgrp * 8) * 2));
            short8 af1 = *(const short8*)(xlds +
                swz(((1 * 16 + lrow) * 128 + ks * 32 + lgrp * 8) * 2));
#pragma unroll
            for (int nt = 0; nt < 2; ++nt) {
                acc[0][nt] = __builtin_amdgcn_mfma_f32_16x16x32_bf16(
                    af0, wf0[nt][ks], acc[0][nt], 0, 0, 0);
                acc[1][nt] = __builtin_amdgcn_mfma_f32_16x16x32_bf16(
                    af1, wf0[nt][ks], acc[1][nt], 0, 0, 0);
            }
        }

        // ---- permutation scatter: C1[r][n] -> flat[n*32 + r] (bf16 into a2lds) ----
        // lane's 4 regs are consecutive r at fixed n -> one ds_write_b64
#pragma unroll
        for (int mt = 0; mt < 2; ++mt)
#pragma unroll
            for (int nt = 0; nt < 2; ++nt) {
                const int n  = (wid * 2 + nt) * 16 + lrow;
                const int r0 = mt * 16 + lgrp * 4;
                u32x2 v;
                v[0] = f2bf1(acc[mt][nt][0]) | (f2bf1(acc[mt][nt][1]) << 16);
                v[1] = f2bf1(acc[mt][nt][2]) | (f2bf1(acc[mt][nt][3]) << 16);
                *(u32x2*)(a2lds + swz((n * 32 + r0) * 2)) = v;
            }
        __syncthreads();  // B1: a2lds ready; xlds reads done

        // ---- step 2: C2 = A2 * W2 ----
        f32x4 acc2[2][2];
#pragma unroll
        for (int mt = 0; mt < 2; ++mt)
#pragma unroll
            for (int nt = 0; nt < 2; ++nt)
                acc2[mt][nt] = (f32x4){0.f, 0.f, 0.f, 0.f};
#pragma unroll
        for (int ks = 0; ks < 4; ++ks) {
            short8 af0 = *(const short8*)(a2lds +
                swz(((0 * 16 + lrow) * 128 + ks * 32 + lgrp * 8) * 2));
            short8 af1 = *(const short8*)(a2lds +
                swz(((1 * 16 + lrow) * 128 + ks * 32 + lgrp * 8) * 2));
#pragma unroll
            for (int nt = 0; nt < 2; ++nt) {
                acc2[0][nt] = __builtin_amdgcn_mfma_f32_16x16x32_bf16(
                    af0, wf1[nt][ks], acc2[0][nt], 0, 0, 0);
                acc2[1][nt] = __builtin_amdgcn_mfma_f32_16x16x32_bf16(
                    af1, wf1[nt][ks], acc2[1][nt], 0, 0, 0);
            }
        }

        // ---- wave-private output re-layout (no barrier: obuf slice is wave-own,
        // DS pipe is in-order per wave) ----
        // value (mt,nt,j): token-flat float idx = n*32 + r, n = wid*32+nt*16+lrow,
        // r = mt*16+lgrp*4+j -> local (4KB wave slice) byte off:
        uint8_t* ob = obuf + wid * 4096;
#pragma unroll
        for (int mt = 0; mt < 2; ++mt)
#pragma unroll
            for (int nt = 0; nt < 2; ++nt) {
                const int loc = (nt * 16 + lrow) * 128 + mt * 64 + lgrp * 16;
                *(f32x4*)(ob + swz(loc)) = acc2[mt][nt];
            }
        // read back linear -> fully contiguous global store (1KB per wave per instr)
        float* op = out + (size_t)t * 4096 + wid * 1024;
#pragma unroll
        for (int i = 0; i < 4; ++i) {
            f32x4 o = *(const f32x4*)(ob + swz(i * 1024 + lane * 16));
            *(f32x4*)(op + i * 256 + lane * 4) = o;
        }
        // no barrier needed here: next iter's B0 orders a2lds reads vs writes,
        // and B1 already ordered xlds reads vs next iter's xlds writes.
    }
}

extern "C" void kernel_launch(void* const* d_in, const int* in_sizes, int n_in,
                              void* d_out, int out_size, void* d_ws, size_t ws_size,
                              hipStream_t stream) {
    const float* x  = (const float*)d_in[0];
    const float* w1 = (const float*)d_in[1];
    const float* w2 = (const float*)d_in[2];
    float* out = (float*)d_out;
    const int ntok = in_sizes[0] / 4096;  // 32768 for the bench shape
    const int nwg = 2048;
    hipLaunchKernelGGL(bl_kernel, dim3(nwg), dim3(256), 0, stream,
                       x, w1, w2, out, ntok);
}